// Round 8
// baseline (163.213 us; speedup 1.0000x reference)
//
#include <hip/hip_runtime.h>

#define CCH 256
#define WH 4096

typedef short bf16x8 __attribute__((ext_vector_type(8)));
typedef float f32x4  __attribute__((ext_vector_type(4)));
typedef unsigned u32x4 __attribute__((ext_vector_type(4)));

// RNE float -> bf16 bits (integer-only, no HIP bf16 structs)
__device__ __forceinline__ unsigned f2bf(float f) {
  unsigned u = __builtin_bit_cast(unsigned, f);
  u += 0x7fffu + ((u >> 16) & 1u);
  return (u >> 16) & 0xffffu;
}
__device__ __forceinline__ float bf2f(unsigned s) {
  return __builtin_bit_cast(float, s << 16);
}

// Truncation split of 2 floats -> packed hi shorts + packed RNE lo shorts.
// hi = top 16 bits of f (exact as float); lo = bf16_rne(f - hi).
__device__ __forceinline__ void split2(float f0, float f1, unsigned& hiw, unsigned& low) {
  const unsigned u0 = __builtin_bit_cast(unsigned, f0);
  const unsigned u1 = __builtin_bit_cast(unsigned, f1);
  hiw = (u0 >> 16) | (u1 & 0xFFFF0000u);
  const float h0 = __builtin_bit_cast(float, u0 & 0xFFFF0000u);
  const float h1 = __builtin_bit_cast(float, u1 & 0xFFFF0000u);
  low = f2bf(f0 - h0) | (f2bf(f1 - h1) << 16);
}

// ---------------------------------------------------------------------------
// Pre-kernel: pack W' = [Wq;Wk] (64 x 256) into MFMA A-fragments, split bf16.
// Frag index f = kt*4 + mt (kt-major so phase 1 streams per-kt contiguously).
// Element (f, lane, t) = W'[mt*16 + (lane&15)][kt*32 + ((lane>>4)&3)*8 + t].
// hi at ws[0..16383] shorts, lo at ws[16384..32767].
// ---------------------------------------------------------------------------
__global__ __launch_bounds__(256) void wsplit_kernel(
    const float* __restrict__ Wq, const float* __restrict__ Wk,
    short* __restrict__ ws) {
  const int gid    = blockIdx.x * 256 + threadIdx.x;   // 0..2047
  const int fragid = gid >> 6;
  const int lane   = gid & 63;
  const int mt = fragid & 3;
  const int kt = fragid >> 2;
  const int dp = mt * 16 + (lane & 15);
  const int cb = kt * 32 + ((lane >> 4) & 3) * 8;
  const float* Wrow = (dp < 32) ? (Wq + (size_t)dp * CCH)
                                : (Wk + (size_t)(dp - 32) * CCH);
  bf16x8 hfr, lfr;
  #pragma unroll
  for (int t = 0; t < 8; ++t) {
    const float v = Wrow[cb + t];
    const unsigned h = f2bf(v);
    hfr[t] = (short)h;
    lfr[t] = (short)f2bf(v - bf2f(h));
  }
  *(bf16x8*)(ws + (size_t)gid * 8)         = hfr;
  *(bf16x8*)(ws + 16384 + (size_t)gid * 8) = lfr;
}

// ---------------------------------------------------------------------------
// Main kernel: one block per (b, w); 4 waves.
// ---------------------------------------------------------------------------
__global__ __launch_bounds__(256)
__attribute__((amdgpu_waves_per_eu(4, 4)))
void selfattn_kernel(
    const float* __restrict__ x, const short* __restrict__ ws,
    float* __restrict__ out) {
  __shared__ float    q_lds[32 * 64];    // [d][h]
  __shared__ float    k_lds[64 * 36];    // [j][d], pad 36 (16B-aligned rows)
  __shared__ unsigned attn32[8 * 8 * 64];// [frag f][t][lane]  hi | lo<<16
  __shared__ float    red1[4 * 64];      // cross-wave max
  __shared__ float    red2[4 * 64];      // cross-wave sum

  const int tid  = threadIdx.x;
  const int lane = tid & 63;
  const int wave = tid >> 6;
  const int g    = lane >> 4;
  const int r16  = lane & 15;
  const int blk  = blockIdx.x;
  const int b    = blk >> 6;
  const int w    = blk & 63;

  const float* xb = x   + (size_t)b * CCH * WH + (size_t)w * 64;
  float*       ob = out + (size_t)b * CCH * WH + (size_t)w * 64;

  // ============ Phase 1: projections q'[d'][h] via split-bf16 MFMA ==========
  // C[d'][h] = sum_c W'[d'][c] * x[c][h].  Wave owns n-tile nt=wave (16 h's).
  {
    const int col = wave * 16 + r16;           // this lane's h column
    f32x4 acc[4] = {{0,0,0,0},{0,0,0,0},{0,0,0,0},{0,0,0,0}};
    #pragma unroll
    for (int kt = 0; kt < 8; ++kt) {
      // B-frag (x): element t = x[kt*32 + g*8 + t][col]
      float xs[8];
      #pragma unroll
      for (int t = 0; t < 8; ++t)
        xs[t] = xb[(size_t)(kt*32 + g*8 + t) * WH + col];
      unsigned hw[4], lw[4];
      #pragma unroll
      for (int r = 0; r < 4; ++r) split2(xs[2*r], xs[2*r+1], hw[r], lw[r]);
      const bf16x8 xbh = __builtin_bit_cast(bf16x8, (u32x4){hw[0],hw[1],hw[2],hw[3]});
      const bf16x8 xbl = __builtin_bit_cast(bf16x8, (u32x4){lw[0],lw[1],lw[2],lw[3]});
      #pragma unroll
      for (int mt = 0; mt < 4; ++mt) {
        const bf16x8 ah = *(const bf16x8*)(ws + (size_t)((kt*4 + mt)*64 + lane) * 8);
        const bf16x8 al = *(const bf16x8*)(ws + 16384 + (size_t)((kt*4 + mt)*64 + lane) * 8);
        acc[mt] = __builtin_amdgcn_mfma_f32_16x16x32_bf16(ah, xbh, acc[mt], 0, 0, 0);
        acc[mt] = __builtin_amdgcn_mfma_f32_16x16x32_bf16(ah, xbl, acc[mt], 0, 0, 0);
        acc[mt] = __builtin_amdgcn_mfma_f32_16x16x32_bf16(al, xbh, acc[mt], 0, 0, 0);
      }
    }
    // C/D: row d' = mt*16 + g*4 + r, col h = wave*16 + r16
    #pragma unroll
    for (int mt = 0; mt < 2; ++mt)
      #pragma unroll
      for (int r = 0; r < 4; ++r)
        q_lds[(mt*16 + g*4 + r) * 64 + col] = acc[mt][r];       // q: [d][h]
    #pragma unroll
    for (int mt = 2; mt < 4; ++mt)
      #pragma unroll
      for (int r = 0; r < 4; ++r)
        k_lds[col * 36 + (mt-2)*16 + g*4 + r] = acc[mt][r];     // k: [j][d]
  }
  __syncthreads();

  // ============ Phase 2: energy + softmax, lane = h (row-local) =============
  float qreg[32];
  #pragma unroll
  for (int d = 0; d < 32; ++d) qreg[d] = q_lds[d * 64 + lane];

  float e[16];
  #pragma unroll
  for (int jj = 0; jj < 16; ++jj) {
    const float4* kr = (const float4*)&k_lds[(wave*16 + jj) * 36];  // uniform bcast
    float acc = 0.f;
    #pragma unroll
    for (int d4 = 0; d4 < 8; ++d4) {
      const float4 kv = kr[d4];
      acc += qreg[4*d4+0]*kv.x + qreg[4*d4+1]*kv.y
           + qreg[4*d4+2]*kv.z + qreg[4*d4+3]*kv.w;
    }
    e[jj] = acc;
  }
  // in-register max tree over this wave's 16 j's
  float pm = e[0];
  #pragma unroll
  for (int jj = 1; jj < 16; ++jj) pm = fmaxf(pm, e[jj]);
  red1[wave*64 + lane] = pm;
  __syncthreads();
  const float m = fmaxf(fmaxf(red1[lane], red1[64 + lane]),
                        fmaxf(red1[128 + lane], red1[192 + lane]));
  float s = 0.f;
  #pragma unroll
  for (int jj = 0; jj < 16; ++jj) { e[jj] = __expf(e[jj] - m); s += e[jj]; }
  red2[wave*64 + lane] = s;
  __syncthreads();
  const float stot = (red2[lane] + red2[64 + lane]) + (red2[128 + lane] + red2[192 + lane]);
  const float rs = 1.0f / stot;
  // write attn directly in phase-3 B-frag layout:
  // B[j][i] = attn[i=h][j]; f = it*2+ks = (lane>>4)*2 + (wave>>1),
  // t = jj&7, l = ((wave&1)*2 + (jj>>3))<<4 | (lane&15)
  {
    const int fbase = (lane >> 4) * 2 + (wave >> 1);
    #pragma unroll
    for (int jj = 0; jj < 16; ++jj) {
      const float p = e[jj] * rs;
      const unsigned u = __builtin_bit_cast(unsigned, p);
      const float hif = __builtin_bit_cast(float, u & 0xFFFF0000u);
      const unsigned lo = f2bf(p - hif);
      const int l2 = (((wave & 1) * 2 + (jj >> 3)) << 4) | r16;
      attn32[fbase*512 + (jj & 7)*64 + l2] = (u >> 16) | (lo << 16);
    }
  }
  __syncthreads();

  // ============ Phase 3: out[c][i] = sum_j x[c][j]*attn[i][j], gate =========
  // A = x rows (lane: A[ct*16+r16][ks*32+g*8+t]); B from attn32 frags.
  const int c0w = wave * 64;
  #pragma unroll
  for (int half = 0; half < 2; ++half) {
    bf16x8 bh[2][2], bl[2][2];                  // [itl][ks]
    #pragma unroll
    for (int itl = 0; itl < 2; ++itl)
      #pragma unroll
      for (int ks = 0; ks < 2; ++ks) {
        const int f = (half*2 + itl)*2 + ks;
        unsigned wv[8];
        #pragma unroll
        for (int t = 0; t < 8; ++t) wv[t] = attn32[f*512 + t*64 + lane];
        u32x4 hwv, lwv;
        #pragma unroll
        for (int r = 0; r < 4; ++r) {
          hwv[r] = (wv[2*r] & 0xFFFFu) | (wv[2*r+1] << 16);
          lwv[r] = (wv[2*r] >> 16)     | (wv[2*r+1] & 0xFFFF0000u);
        }
        bh[itl][ks] = __builtin_bit_cast(bf16x8, hwv);
        bl[itl][ks] = __builtin_bit_cast(bf16x8, lwv);
      }
    #pragma unroll
    for (int ct = 0; ct < 4; ++ct) {
      const int crow = c0w + ct*16 + r16;
      const float4* xrow = (const float4*)(xb + (size_t)crow * WH);
      bf16x8 xh[2], xl[2];
      #pragma unroll
      for (int ks = 0; ks < 2; ++ks) {
        const float4 fa = xrow[ks*8 + g*2];
        const float4 fb = xrow[ks*8 + g*2 + 1];
        unsigned hw[4], lw[4];
        split2(fa.x, fa.y, hw[0], lw[0]);
        split2(fa.z, fa.w, hw[1], lw[1]);
        split2(fb.x, fb.y, hw[2], lw[2]);
        split2(fb.z, fb.w, hw[3], lw[3]);
        xh[ks] = __builtin_bit_cast(bf16x8, (u32x4){hw[0],hw[1],hw[2],hw[3]});
        xl[ks] = __builtin_bit_cast(bf16x8, (u32x4){lw[0],lw[1],lw[2],lw[3]});
      }
      #pragma unroll
      for (int itl = 0; itl < 2; ++itl) {
        f32x4 acc = {0.f, 0.f, 0.f, 0.f};
        #pragma unroll
        for (int ks = 0; ks < 2; ++ks) {
          acc = __builtin_amdgcn_mfma_f32_16x16x32_bf16(xh[ks], bh[itl][ks], acc, 0, 0, 0);
          acc = __builtin_amdgcn_mfma_f32_16x16x32_bf16(xh[ks], bl[itl][ks], acc, 0, 0, 0);
          acc = __builtin_amdgcn_mfma_f32_16x16x32_bf16(xl[ks], bh[itl][ks], acc, 0, 0, 0);
        }
        const int i = (half*2 + itl)*16 + r16;
        #pragma unroll
        for (int r = 0; r < 4; ++r) {
          const int c = c0w + ct*16 + g*4 + r;
          const float xg = xb[(size_t)c * WH + i];
          ob[(size_t)c * WH + i] = acc[r] * xg;
        }
      }
    }
  }
}

extern "C" void kernel_launch(void* const* d_in, const int* in_sizes, int n_in,
                              void* d_out, int out_size, void* d_ws, size_t ws_size,
                              hipStream_t stream) {
  (void)in_sizes; (void)n_in; (void)out_size; (void)ws_size;
  const float* x  = (const float*)d_in[0];
  const float* Wq = (const float*)d_in[1];
  const float* Wk = (const float*)d_in[2];
  float* out = (float*)d_out;
  hipLaunchKernelGGL(wsplit_kernel, dim3(8), dim3(256), 0, stream,
                     Wq, Wk, (short*)d_ws);
  hipLaunchKernelGGL(selfattn_kernel, dim3(16 * 64), dim3(256), 0, stream,
                     x, (const short*)d_ws, out);
}